// Round 6
// baseline (84.066 us; speedup 1.0000x reference)
//
#include <hip/hip_runtime.h>
#include <hip/hip_bf16.h>
#include <stdint.h>

// LinearAssignmentLossCE, O(E+T), TWO dispatches (memset + one kernel),
// bit-deterministic.
//
// For target t=(a,b):
//   K    = cntS[a] + cntD[b] - cntBoth(a,b)
//   lse  = log( sumS[a] + sumD[b] - sumBoth(a,b) )   (sums of exp(score))
//   idx  = min{ e : src[e]==a && dst[e]==b }
//   loss = exists ? (lse - score[idx]) / K : 0
// out = sum_t loss / T
//
// Evolution: R1 brute force 113us (VALU wall) -> R2 hash join 88us (1-block
// latency wall) -> R3 coop fusion 103us (525K fabric atomics) -> R4 target-
// keyed hash + packed u64 fixed-point atomics, 6 dispatches, 36us -> R5
// 4 dispatches, 33us (dispatch-boundary bound).
// R6: everything zero-initializable (EMPTY=0 via key=(s+1)<<32|d; argmin via
// atomicMax of ~e) -> ONE 420KB memset + ONE kernel with software grid
// barriers (release fetch_add / acquire spin, AGENT scope -- the same
// release/acquire pattern R5's last-block finish validated). 128 blocks x
// 512 thr = 1024 waves << 8192-wave capacity -> co-residency guaranteed,
// no deadlock. Cross-phase producer writes are all device-scope atomics;
// each barrier acquire invalidates L1/L2 before consumers' plain loads.
//
// Fixed-point packing: (cnt<<40) | round(exp(score)*2^22) in one u64
// atomicAdd -> integer inclusion-exclusion is exact and order-independent;
// output is bit-identical across replays.

#define HLOG 13
#define HSZ  (1u << HLOG)        // 8192 slots for <=4096 target keys
#define NCAP 16384               // node ids < 16384 (N=10000)
#define NBW  (NCAP / 32)
#define M40     ((1ull << 40) - 1)
#define CNT1    (1ull << 40)
#define FSCALE      4194304.0f   // 2^22
#define INV_FSCALE  (1.0f / 4194304.0f)

#define NBLK 128
#define TPB  512
#define NTH  (NBLK * TPB)        // 65536 = E (one edge per thread)

typedef unsigned long long u64;
typedef unsigned int u32;

__device__ __forceinline__ u32 hash64(u64 k) {
    return (u32)((k * 0x9E3779B97F4A7C15ull) >> (64 - HLOG));  // Fibonacci
}

// Monotonic-flag grid barrier. bar[0]=flag, bar[1+phase]=arrival counter.
// All words zeroed by the memset each call.
__device__ __forceinline__ void gbar(u32* bar, int phase, int nblk) {
    __syncthreads();
    if (threadIdx.x == 0) {
        const u32 prev = __hip_atomic_fetch_add(&bar[1 + phase], 1u,
                                                __ATOMIC_ACQ_REL,
                                                __HIP_MEMORY_SCOPE_AGENT);
        if (prev == (u32)(nblk - 1)) {
            __hip_atomic_store(&bar[0], (u32)(phase + 1), __ATOMIC_RELEASE,
                               __HIP_MEMORY_SCOPE_AGENT);
        } else {
            while (__hip_atomic_load(&bar[0], __ATOMIC_ACQUIRE,
                                     __HIP_MEMORY_SCOPE_AGENT) <= (u32)phase) {}
        }
    }
    __syncthreads();  // extends thread-0's acquire (L1 is per-CU) block-wide
}

__global__ __launch_bounds__(TPB) void la_onekernel(
    const int* __restrict__ src, const int* __restrict__ dst,
    const float* __restrict__ score,
    const int* __restrict__ tsrc, const int* __restrict__ tdst,
    u64* __restrict__ hkey, u64* __restrict__ hpack,
    u64* __restrict__ nodeS, u64* __restrict__ nodeD,
    u32* __restrict__ hmax, u32* __restrict__ sbit, u32* __restrict__ dbit,
    u32* __restrict__ bar, float* __restrict__ wpart,
    float* __restrict__ out, int E, int T)
{
    const int gtid = blockIdx.x * TPB + threadIdx.x;
    const int nblk = gridDim.x;

    // ---- P1: insert target keys + node bitmaps (atomic writes only) ------
    for (int t = gtid; t < T; t += NTH) {
        const u32 a = (u32)tsrc[t], b = (u32)tdst[t];
        if (a < NCAP) atomicOr(&sbit[a >> 5], 1u << (a & 31));
        if (b < NCAP) atomicOr(&dbit[b >> 5], 1u << (b & 31));
        const u64 key = ((u64)(a + 1) << 32) | b;   // key != 0 always
        u32 h = hash64(key);
        while (true) {
            const u64 prev = atomicCAS(&hkey[h], 0ull, key);
            if (prev == 0ull || prev == key) break;
            h = (h + 1) & (HSZ - 1);
        }
    }
    gbar(bar, 0, nblk);

    // ---- P2: edge aggregation (bitmap-filtered, atomic writes only) ------
    for (int e = gtid; e < E; e += NTH) {
        const u32 s = (u32)src[e], d = (u32)dst[e];
        const float sc = score[e];                  // coalesced; cheap
        const bool hs = (s < NCAP) && ((sbit[s >> 5] >> (s & 31)) & 1u);
        const bool hd = (d < NCAP) && ((dbit[d >> 5] >> (d & 31)) & 1u);
        if (hs | hd) {
            const u64 add = (u64)(__expf(sc) * FSCALE + 0.5f) + CNT1;
            if (hs) atomicAdd(&nodeS[s], add);
            if (hd) atomicAdd(&nodeD[d], add);
            if (hs & hd) {
                const u64 key = ((u64)(s + 1) << 32) | d;
                u32 h = hash64(key);
                while (true) {
                    const u64 k2 = hkey[h];
                    if (k2 == 0ull) break;          // not a target edge
                    if (k2 == key) {
                        atomicAdd(&hpack[h], add);
                        atomicMax(&hmax[h], ~(u32)e);  // argmin via max of ~e
                        break;
                    }
                    h = (h + 1) & (HSZ - 1);
                }
            }
        }
    }
    gbar(bar, 1, nblk);

    // ---- P3: target lookups -> per-wave partials -------------------------
    float local = 0.0f;
    for (int t = gtid; t < T; t += NTH) {
        const u32 a = (u32)tsrc[t], b = (u32)tdst[t];
        const u64 key = ((u64)(a + 1) << 32) | b;
        u32 h = hash64(key);
        int slot = -1;
        while (true) {
            const u64 k2 = hkey[h];
            if (k2 == key) { slot = (int)h; break; }
            if (k2 == 0ull) break;  // defensive; key was inserted in P1
            h = (h + 1) & (HSZ - 1);
        }
        if (slot >= 0) {
            const u64 pk = hpack[slot];
            const u64 cb = pk >> 40;
            if (cb > 0) {           // target edge exists among edges
                const u64 pa = nodeS[a], pb = nodeD[b];
                const u64 Sfix = (pa & M40) + (pb & M40) - (pk & M40); // exact
                const u64 Kc   = (pa >> 40) + (pb >> 40) - cb;
                const int idx  = (int)(~hmax[slot]);
                local += (logf((float)Sfix * INV_FSCALE) - score[idx])
                         / (float)Kc;
            }
        }
    }
    for (int off = 32; off > 0; off >>= 1) local += __shfl_down(local, off);

    const int nw  = ((T + 63) / 64 < NTH / 64) ? (T + 63) / 64 : NTH / 64;
    const int wid = gtid >> 6;
    if ((threadIdx.x & 63) == 0 && wid < nw)
        __hip_atomic_store(&wpart[wid], local, __ATOMIC_RELEASE,
                           __HIP_MEMORY_SCOPE_AGENT);
    gbar(bar, 2, nblk);

    // ---- P4: block 0 does the fixed-order final reduce -------------------
    if (blockIdx.x == 0) {
        float s2 = 0.0f;
        for (int i = threadIdx.x; i < nw; i += TPB) s2 += wpart[i];
        for (int off = 32; off > 0; off >>= 1) s2 += __shfl_down(s2, off);
        __shared__ float acc[TPB / 64];
        if ((threadIdx.x & 63) == 0) acc[threadIdx.x >> 6] = s2;
        __syncthreads();
        if (threadIdx.x == 0) {
            float r = 0.0f;
#pragma unroll
            for (int w = 0; w < TPB / 64; ++w) r += acc[w];
            out[0] = r / (float)T;
        }
    }
}

// ---------------------------------------------------------------------------
// Fallback (ws too small): round-1 brute force, needs T*4 bytes of ws.
// ---------------------------------------------------------------------------
#define NT   8
#define BLK  256

__global__ __launch_bounds__(BLK) void la_loss_main(
    const int* __restrict__ src, const int* __restrict__ dst,
    const float* __restrict__ score,
    const int* __restrict__ tsrc, const int* __restrict__ tdst,
    float* __restrict__ partial, int E, int T)
{
    const int tid   = threadIdx.x;
    const int tbase = blockIdx.x * NT;
    if (tbase >= T) return;

    int ts[NT], td[NT];
#pragma unroll
    for (int j = 0; j < NT; ++j) {
        int tj = tbase + j; if (tj > T - 1) tj = T - 1;
        ts[j] = tsrc[tj];
        td[j] = tdst[tj];
    }

    float S[NT]; float Kc[NT]; int idx[NT];
#pragma unroll
    for (int j = 0; j < NT; ++j) { S[j] = 0.0f; Kc[j] = 0.0f; idx[j] = 0x7fffffff; }

    for (int it = tid * 4; it < E; it += BLK * 4) {
        const int4   vs = *reinterpret_cast<const int4*>(src + it);
        const int4   vd = *reinterpret_cast<const int4*>(dst + it);
        const float4 sc = *reinterpret_cast<const float4*>(score + it);
        const int   es[4] = { vs.x, vs.y, vs.z, vs.w };
        const int   ed[4] = { vd.x, vd.y, vd.z, vd.w };
        const float ev[4] = { __expf(sc.x), __expf(sc.y), __expf(sc.z), __expf(sc.w) };
#pragma unroll
        for (int j = 0; j < NT; ++j) {
#pragma unroll
            for (int k = 0; k < 4; ++k) {
                const bool ms = (es[k] == ts[j]);
                const bool md = (ed[k] == td[j]);
                const bool m  = ms | md;
                S[j]  += m ? ev[k] : 0.0f;
                Kc[j] += m ? 1.0f  : 0.0f;
                idx[j] = (ms & md) ? min(idx[j], it + k) : idx[j];
            }
        }
    }

#pragma unroll
    for (int j = 0; j < NT; ++j) {
        for (int off = 32; off > 0; off >>= 1) {
            S[j]  += __shfl_down(S[j],  off);
            Kc[j] += __shfl_down(Kc[j], off);
            idx[j] = min(idx[j], __shfl_down(idx[j], off));
        }
    }

    __shared__ float sS[4][NT];
    __shared__ float sK[4][NT];
    __shared__ int   sI[4][NT];
    const int wave = tid >> 6;
    const int lane = tid & 63;
    if (lane == 0) {
#pragma unroll
        for (int j = 0; j < NT; ++j) { sS[wave][j] = S[j]; sK[wave][j] = Kc[j]; sI[wave][j] = idx[j]; }
    }
    __syncthreads();

    if (tid < NT && (tbase + tid) < T) {
        float Ssum = 0.0f, Ksum = 0.0f;
        int im = 0x7fffffff;
#pragma unroll
        for (int w = 0; w < 4; ++w) {
            Ssum += sS[w][tid]; Ksum += sK[w][tid]; im = min(im, sI[w][tid]);
        }
        float loss = 0.0f;
        if (im != 0x7fffffff) loss = (logf(Ssum) - score[im]) / Ksum;
        partial[tbase + tid] = loss;
    }
}

__global__ __launch_bounds__(256) void la_loss_reduce(
    const float* __restrict__ partial, float* __restrict__ out, int T)
{
    float s = 0.0f;
    for (int i = threadIdx.x; i < T; i += 256) s += partial[i];
    for (int off = 32; off > 0; off >>= 1) s += __shfl_down(s, off);
    __shared__ float acc[4];
    if ((threadIdx.x & 63) == 0) acc[threadIdx.x >> 6] = s;
    __syncthreads();
    if (threadIdx.x == 0) out[0] = (acc[0] + acc[1] + acc[2] + acc[3]) / (float)T;
}

// ---------------------------------------------------------------------------

extern "C" void kernel_launch(void* const* d_in, const int* in_sizes, int n_in,
                              void* d_out, int out_size, void* d_ws, size_t ws_size,
                              hipStream_t stream) {
    const int*   edge_index = (const int*)d_in[0];   // (2, E) int32
    const float* score      = (const float*)d_in[1]; // (E,)   f32
    const int*   target     = (const int*)d_in[2];   // (2, T) int32
    // d_in[3] = num_nodes (device scalar) -- unused: keys are (src+1,dst)

    const int E = in_sizes[0] / 2;
    const int T = in_sizes[2] / 2;

    const int* src  = edge_index;
    const int* dst  = edge_index + E;
    const int* tsrc = target;
    const int* tdst = target + T;

    // ws layout (u64 arrays first; everything zero-init by ONE memset):
    //   hkey  u64[HSZ]    64KB
    //   hpack u64[HSZ]    64KB
    //   nodeS u64[NCAP]  128KB
    //   nodeD u64[NCAP]  128KB
    //   hmax  u32[HSZ]    32KB
    //   sbit  u32[NBW]     2KB
    //   dbit  u32[NBW]     2KB
    //   bar   u32[8]       32B
    //   wpart f32[nw]
    const int nw = ((T + 63) / 64 < NTH / 64) ? (T + 63) / 64 : NTH / 64;
    const size_t need = (size_t)HSZ * 8 * 2 + (size_t)NCAP * 8 * 2
                      + (size_t)HSZ * 4 + 2 * (size_t)NBW * 4 + 32
                      + (size_t)nw * 4;

    if (ws_size >= need) {
        uint8_t* p = (uint8_t*)d_ws;
        u64* hkey  = (u64*)p;                          p += (size_t)HSZ * 8;
        u64* hpack = (u64*)p;                          p += (size_t)HSZ * 8;
        u64* nodeS = (u64*)p;                          p += (size_t)NCAP * 8;
        u64* nodeD = (u64*)p;                          p += (size_t)NCAP * 8;
        u32* hmax  = (u32*)p;                          p += (size_t)HSZ * 4;
        u32* sbit  = (u32*)p;                          p += (size_t)NBW * 4;
        u32* dbit  = (u32*)p;                          p += (size_t)NBW * 4;
        u32* bar   = (u32*)p;                          p += 32;
        float* wpart = (float*)p;

        hipMemsetAsync(d_ws, 0, need, stream);
        la_onekernel<<<NBLK, TPB, 0, stream>>>(src, dst, score, tsrc, tdst,
                                               hkey, hpack, nodeS, nodeD,
                                               hmax, sbit, dbit, bar, wpart,
                                               (float*)d_out, E, T);
    } else {
        float* partial = (float*)d_ws;  // T floats
        la_loss_main<<<(T + NT - 1) / NT, BLK, 0, stream>>>(src, dst, score,
                                                            tsrc, tdst, partial, E, T);
        la_loss_reduce<<<1, 256, 0, stream>>>(partial, (float*)d_out, T);
    }
}

// Round 7
// 33.518 us; speedup vs baseline: 2.5081x; 2.5081x over previous
//
#include <hip/hip_runtime.h>
#include <hip/hip_bf16.h>
#include <stdint.h>

// LinearAssignmentLossCE, O(E+T), THREE dispatches, bit-deterministic.
//
// For target t=(a,b):
//   K    = cntS[a] + cntD[b] - cntBoth(a,b)
//   lse  = log( sumS[a] + sumD[b] - sumBoth(a,b) )   (sums of exp(score))
//   idx  = min{ e : src[e]==a && dst[e]==b }
//   loss = exists ? (lse - score[idx]) / K : 0
// out = sum_t loss / T
//
// Evolution: R1 brute 113us (VALU wall) -> R2 88us (1-block latency wall) ->
// R3 coop fusion 103us (grid.sync + fabric atomics) -> R4 36us (target-keyed
// hash, 6 dispatches) -> R5 33us (4 dispatches) -> R6 84us REGRESSION:
// software grid barriers cost ~20-25us EACH on MI355X (127 spinners on one
// line serialize at the home L2) -- grid-wide sync belongs at dispatch
// boundaries only.
// R7: remove the insert phase's global-ordering need altogether. The join
// structures (pair hash + node bitmaps) are pure functions of the tiny
// target list, so EVERY block builds them redundantly in its own LDS
// (block-local atomics, zero fabric traffic); __syncthreads() orders
// build->probe within the block. Global state is only the integer
// accumulators (zeroed by one memset). 3 dispatches:
//   memset(320KB) -> merge1(LDS build + edge aggregation) -> targets.
//
// Fixed-point packing: (cnt<<40) | round(exp(score)*2^22) in one u64
// atomicAdd -> inclusion-exclusion is integer-exact and order-independent;
// output is bit-identical across replays. exp(score)<=~120 for N(0,1),
// degree <~ 40 -> fix sums < 2^33 << 2^40.

#define NCAP 16384               // node ids < 16384 (N=10000); key = a*16384+b < 2^28
#define NBW  (NCAP / 32)         // 512 bitmap words (2KB)
#define HLOG 13
#define HSZ  (1u << HLOG)        // 8192 LDS slots for <=4096 target keys
#define M40     ((1ull << 40) - 1)
#define CNT1    (1ull << 40)
#define FSCALE      4194304.0f   // 2^22
#define INV_FSCALE  (1.0f / 4194304.0f)

#define NBLK 128
#define TPB  512

typedef unsigned long long u64;
typedef unsigned int u32;

__device__ __forceinline__ u32 hash28(u32 k) {
    return (k * 2654435761u) >> (32 - HLOG);
}

// min-update a u16 half of a shared u32 word via CAS retry
__device__ __forceinline__ void lds_min_u16(u32* word, int hi, u32 t) {
    u32 old = *word;
    while (true) {
        const u32 cur = hi ? (old >> 16) : (old & 0xFFFFu);
        if (t >= cur) break;
        const u32 nw = hi ? ((old & 0x0000FFFFu) | (t << 16))
                          : ((old & 0xFFFF0000u) | t);
        const u32 prev = atomicCAS(word, old, nw);
        if (prev == old) break;
        old = prev;
    }
}

// ---- K1: per-block LDS join-structure build + edge aggregation ------------
__global__ __launch_bounds__(TPB) void la_merge(
    const int* __restrict__ src, const int* __restrict__ dst,
    const float* __restrict__ score,
    const int* __restrict__ tsrc, const int* __restrict__ tdst,
    u64* __restrict__ nodeS, u64* __restrict__ nodeD,
    u64* __restrict__ bothPack, u32* __restrict__ bothMax,
    u32* __restrict__ canon, int E, int T)
{
    __shared__ u32 keys[HSZ];         // 32KB, 0xFFFFFFFF = empty (keys < 2^28)
    __shared__ u32 valw[HSZ / 2];     // 16KB, packed u16 min-target-idx
    __shared__ u32 sbits[NBW];        //  2KB
    __shared__ u32 dbits[NBW];        //  2KB

    const int tid = threadIdx.x;

    // LDS init
    for (int i = tid; i < HSZ; i += TPB)      keys[i] = 0xFFFFFFFFu;
    for (int i = tid; i < HSZ / 2; i += TPB)  valw[i] = 0xFFFFFFFFu;
    for (int i = tid; i < NBW; i += TPB)    { sbits[i] = 0u; dbits[i] = 0u; }
    __syncthreads();

    // Build: every block inserts ALL targets into its own LDS (idempotent
    // content: CAS-claim keys + CAS-min values; block-local races only).
    for (int t = tid; t < T; t += TPB) {
        const u32 a = (u32)tsrc[t], b = (u32)tdst[t];
        if (a >= NCAP || b >= NCAP) continue;   // defensive (N=10000)
        atomicOr(&sbits[a >> 5], 1u << (a & 31));
        atomicOr(&dbits[b >> 5], 1u << (b & 31));
        const u32 key = a * (u32)NCAP + b;      // < 2^28, never 0xFFFFFFFF
        u32 h = hash28(key);
        while (true) {
            const u32 prev = atomicCAS(&keys[h], 0xFFFFFFFFu, key);
            if (prev == 0xFFFFFFFFu || prev == key) break;
            h = (h + 1) & (HSZ - 1);
        }
        lds_min_u16(&valw[h >> 1], h & 1, (u32)t);
    }
    __syncthreads();

    // Block 0 exports the canonical (min) target index per target for K2.
    if (blockIdx.x == 0) {
        for (int t = tid; t < T; t += TPB) {
            const u32 a = (u32)tsrc[t], b = (u32)tdst[t];
            u32 c = (u32)t;
            if (a < NCAP && b < NCAP) {
                const u32 key = a * (u32)NCAP + b;
                u32 h = hash28(key);
                while (true) {
                    const u32 k2 = keys[h];
                    if (k2 == key) {
                        const u32 w = valw[h >> 1];
                        c = (h & 1) ? (w >> 16) : (w & 0xFFFFu);
                        break;
                    }
                    if (k2 == 0xFFFFFFFFu) break;
                    h = (h + 1) & (HSZ - 1);
                }
            }
            canon[t] = c;
        }
    }

    // Edge aggregation: bitmap-filtered node atomics; LDS-hash probe for the
    // exact-pair ("both") term, accumulated at the canonical target index.
    for (int e = blockIdx.x * TPB + tid; e < E; e += NBLK * TPB) {
        const u32 s = (u32)src[e], d = (u32)dst[e];
        if (s >= NCAP || d >= NCAP) continue;   // defensive
        const bool hs = (sbits[s >> 5] >> (s & 31)) & 1u;
        const bool hd = (dbits[d >> 5] >> (d & 31)) & 1u;
        if (!(hs | hd)) continue;               // node never read by a target
        const u64 add = (u64)(__expf(score[e]) * FSCALE + 0.5f) + CNT1;
        if (hs) atomicAdd(&nodeS[s], add);
        if (hd) atomicAdd(&nodeD[d], add);
        if (hs & hd) {
            const u32 key = s * (u32)NCAP + d;
            u32 h = hash28(key);
            while (true) {
                const u32 k2 = keys[h];
                if (k2 == 0xFFFFFFFFu) break;   // not a target pair
                if (k2 == key) {
                    const u32 w = valw[h >> 1];
                    const u32 c = (h & 1) ? (w >> 16) : (w & 0xFFFFu);
                    atomicAdd(&bothPack[c], add);
                    atomicMax(&bothMax[c], ~(u32)e);  // argmin via max of ~e
                    break;
                }
                h = (h + 1) & (HSZ - 1);
            }
        }
    }
}

// ---- K2: target lookup + last-block finish (R5-validated pattern) --------
__global__ __launch_bounds__(64) void la_targets(
    const int* __restrict__ tsrc, const int* __restrict__ tdst,
    const float* __restrict__ score,
    const u64* __restrict__ nodeS, const u64* __restrict__ nodeD,
    const u64* __restrict__ bothPack, const u32* __restrict__ bothMax,
    const u32* __restrict__ canon,
    float* __restrict__ partial, u32* __restrict__ done,
    float* __restrict__ out, int T)
{
    const int nb = gridDim.x;
    const int t  = blockIdx.x * 64 + threadIdx.x;
    float local = 0.0f;
    if (t < T) {
        const u32 a = (u32)tsrc[t], b = (u32)tdst[t];
        if (a < NCAP && b < NCAP) {
            const u32 c  = canon[t];
            const u64 pk = bothPack[c];
            const u64 cb = pk >> 40;
            if (cb > 0) {                   // target edge exists among edges
                const u64 pa = nodeS[a], pb = nodeD[b];
                const u64 Sfix = (pa & M40) + (pb & M40) - (pk & M40); // exact
                const u64 Kc   = (pa >> 40) + (pb >> 40) - cb;
                const int idx  = (int)(~bothMax[c]);
                local = (logf((float)Sfix * INV_FSCALE) - score[idx])
                        / (float)Kc;
            }
        }
    }
    for (int off = 32; off > 0; off >>= 1) local += __shfl_down(local, off);

    __shared__ int lastFlag;
    if (threadIdx.x == 0) {
        __hip_atomic_store(&partial[blockIdx.x], local, __ATOMIC_RELEASE,
                           __HIP_MEMORY_SCOPE_AGENT);
        const u32 prev = __hip_atomic_fetch_add(done, 1u, __ATOMIC_ACQ_REL,
                                                __HIP_MEMORY_SCOPE_AGENT);
        lastFlag = (prev == (u32)(nb - 1));
    }
    __syncthreads();  // extends thread-0's device-acquire block-wide

    if (lastFlag) {
        float s = 0.0f;
        for (int i = threadIdx.x; i < nb; i += 64)
            s += __hip_atomic_load(&partial[i], __ATOMIC_RELAXED,
                                   __HIP_MEMORY_SCOPE_AGENT);
        for (int off = 32; off > 0; off >>= 1) s += __shfl_down(s, off);
        if (threadIdx.x == 0) out[0] = s / (float)T;
    }
}

// ---------------------------------------------------------------------------
// Fallback (ws too small): round-1 brute force, needs T*4 bytes of ws.
// ---------------------------------------------------------------------------
#define NT   8
#define BLK  256

__global__ __launch_bounds__(BLK) void la_loss_main(
    const int* __restrict__ src, const int* __restrict__ dst,
    const float* __restrict__ score,
    const int* __restrict__ tsrc, const int* __restrict__ tdst,
    float* __restrict__ partial, int E, int T)
{
    const int tid   = threadIdx.x;
    const int tbase = blockIdx.x * NT;
    if (tbase >= T) return;

    int ts[NT], td[NT];
#pragma unroll
    for (int j = 0; j < NT; ++j) {
        int tj = tbase + j; if (tj > T - 1) tj = T - 1;
        ts[j] = tsrc[tj];
        td[j] = tdst[tj];
    }

    float S[NT]; float Kc[NT]; int idx[NT];
#pragma unroll
    for (int j = 0; j < NT; ++j) { S[j] = 0.0f; Kc[j] = 0.0f; idx[j] = 0x7fffffff; }

    for (int it = tid * 4; it < E; it += BLK * 4) {
        const int4   vs = *reinterpret_cast<const int4*>(src + it);
        const int4   vd = *reinterpret_cast<const int4*>(dst + it);
        const float4 sc = *reinterpret_cast<const float4*>(score + it);
        const int   es[4] = { vs.x, vs.y, vs.z, vs.w };
        const int   ed[4] = { vd.x, vd.y, vd.z, vd.w };
        const float ev[4] = { __expf(sc.x), __expf(sc.y), __expf(sc.z), __expf(sc.w) };
#pragma unroll
        for (int j = 0; j < NT; ++j) {
#pragma unroll
            for (int k = 0; k < 4; ++k) {
                const bool ms = (es[k] == ts[j]);
                const bool md = (ed[k] == td[j]);
                const bool m  = ms | md;
                S[j]  += m ? ev[k] : 0.0f;
                Kc[j] += m ? 1.0f  : 0.0f;
                idx[j] = (ms & md) ? min(idx[j], it + k) : idx[j];
            }
        }
    }

#pragma unroll
    for (int j = 0; j < NT; ++j) {
        for (int off = 32; off > 0; off >>= 1) {
            S[j]  += __shfl_down(S[j],  off);
            Kc[j] += __shfl_down(Kc[j], off);
            idx[j] = min(idx[j], __shfl_down(idx[j], off));
        }
    }

    __shared__ float sS[4][NT];
    __shared__ float sK[4][NT];
    __shared__ int   sI[4][NT];
    const int wave = tid >> 6;
    const int lane = tid & 63;
    if (lane == 0) {
#pragma unroll
        for (int j = 0; j < NT; ++j) { sS[wave][j] = S[j]; sK[wave][j] = Kc[j]; sI[wave][j] = idx[j]; }
    }
    __syncthreads();

    if (tid < NT && (tbase + tid) < T) {
        float Ssum = 0.0f, Ksum = 0.0f;
        int im = 0x7fffffff;
#pragma unroll
        for (int w = 0; w < 4; ++w) {
            Ssum += sS[w][tid]; Ksum += sK[w][tid]; im = min(im, sI[w][tid]);
        }
        float loss = 0.0f;
        if (im != 0x7fffffff) loss = (logf(Ssum) - score[im]) / Ksum;
        partial[tbase + tid] = loss;
    }
}

__global__ __launch_bounds__(256) void la_loss_reduce(
    const float* __restrict__ partial, float* __restrict__ out, int T)
{
    float s = 0.0f;
    for (int i = threadIdx.x; i < T; i += 256) s += partial[i];
    for (int off = 32; off > 0; off >>= 1) s += __shfl_down(s, off);
    __shared__ float acc[4];
    if ((threadIdx.x & 63) == 0) acc[threadIdx.x >> 6] = s;
    __syncthreads();
    if (threadIdx.x == 0) out[0] = (acc[0] + acc[1] + acc[2] + acc[3]) / (float)T;
}

// ---------------------------------------------------------------------------

extern "C" void kernel_launch(void* const* d_in, const int* in_sizes, int n_in,
                              void* d_out, int out_size, void* d_ws, size_t ws_size,
                              hipStream_t stream) {
    const int*   edge_index = (const int*)d_in[0];   // (2, E) int32
    const float* score      = (const float*)d_in[1]; // (E,)   f32
    const int*   target     = (const int*)d_in[2];   // (2, T) int32
    // d_in[3] = num_nodes (device scalar) -- unused: key = a*NCAP+b

    const int E = in_sizes[0] / 2;
    const int T = in_sizes[2] / 2;

    const int* src  = edge_index;
    const int* dst  = edge_index + E;
    const int* tsrc = target;
    const int* tdst = target + T;

    // ws layout (u64 arrays first; ONE memset zeroes everything):
    //   nodeS    u64[NCAP]  128KB
    //   nodeD    u64[NCAP]  128KB
    //   bothPack u64[T]      32KB
    //   bothMax  u32[T]      16KB
    //   canon    u32[T]      16KB
    //   done     u32[8]      32B
    //   partial  f32[nb]
    const int nb = (T + 63) / 64;
    const size_t need = 2 * (size_t)NCAP * 8 + (size_t)T * 8
                      + 2 * (size_t)T * 4 + 32 + (size_t)nb * 4;

    if (ws_size >= need && T < 65536) {
        uint8_t* p = (uint8_t*)d_ws;
        u64* nodeS    = (u64*)p;  p += (size_t)NCAP * 8;
        u64* nodeD    = (u64*)p;  p += (size_t)NCAP * 8;
        u64* bothPack = (u64*)p;  p += (size_t)T * 8;
        u32* bothMax  = (u32*)p;  p += (size_t)T * 4;
        u32* canon    = (u32*)p;  p += (size_t)T * 4;
        u32* done     = (u32*)p;  p += 32;
        float* partial = (float*)p;

        hipMemsetAsync(d_ws, 0, need, stream);
        la_merge<<<NBLK, TPB, 0, stream>>>(src, dst, score, tsrc, tdst,
                                           nodeS, nodeD, bothPack, bothMax,
                                           canon, E, T);
        la_targets<<<nb, 64, 0, stream>>>(tsrc, tdst, score, nodeS, nodeD,
                                          bothPack, bothMax, canon,
                                          partial, done, (float*)d_out, T);
    } else {
        float* partial = (float*)d_ws;  // T floats
        la_loss_main<<<(T + NT - 1) / NT, BLK, 0, stream>>>(src, dst, score,
                                                            tsrc, tdst, partial, E, T);
        la_loss_reduce<<<1, 256, 0, stream>>>(partial, (float*)d_out, T);
    }
}